// Round 1
// baseline (5782.150 us; speedup 1.0000x reference)
//
#include <hip/hip_runtime.h>
#include <hip/hip_bf16.h>
#include <cstdint>

#define S_LEN 1024
#define DMODEL 1352
#define TD 4056
#define DFFN 2704
#define NHEAD 8
#define HDIM 169
#define NLAYER 7
#define LDAP 1376   // 1352 padded to multiple of 32

typedef __attribute__((ext_vector_type(8))) short short8;
typedef __attribute__((ext_vector_type(4))) float f32x4;

__device__ __forceinline__ unsigned short f2bf(float f) {
    union { float f; unsigned int u; } c; c.f = f;
    unsigned int r = (c.u + 0x7fffu + ((c.u >> 16) & 1u)) >> 16;
    return (unsigned short)r;
}

// ---------------- routing: per-expert token compaction (1 block) ----------------
__global__ __launch_bounds__(256) void route_k(const float* __restrict__ x,
                                               int* __restrict__ perm,
                                               int* __restrict__ pcnt) {
    const int tid = threadIdx.x;
    const int lane = tid & 63;
    const int w = tid >> 6;            // wave id == expert id
    for (int i = tid; i < 4096; i += 256) perm[i] = -1;
    __syncthreads();
    int base = 0;
    for (int c = 0; c < 16; ++c) {
        const int t = c * 64 + lane;
        const float* xr = x + (long long)t * DMODEL;
        float best = xr[0]; int bi = 0;
        #pragma unroll
        for (int j = 1; j < 16; ++j) { float v = xr[j]; if (v > best) { best = v; bi = j; } }
        const bool match = ((bi & 3) == w);
        unsigned long long mb = __ballot(match);
        int pos = __popcll(mb & ((1ull << lane) - 1ull));
        if (match) perm[w * 1024 + base + pos] = t;
        base += __popcll(mb);
    }
    if (lane == 0) pcnt[w] = (base + 127) & ~127;   // padded count (tiles of 128)
}

// ---------------- layernorm -> bf16 (zero-padded to ldo) ----------------
__global__ __launch_bounds__(256) void ln_k(const float* __restrict__ h,
                                            const float* __restrict__ g,
                                            const float* __restrict__ b,
                                            unsigned short* __restrict__ out,
                                            int D, int ldo) {
    const int row = blockIdx.x;
    const float* hr = h + (long long)row * D;
    float s = 0.f, s2 = 0.f;
    for (int j = threadIdx.x; j < D; j += 256) { float v = hr[j]; s += v; s2 += v * v; }
    __shared__ float sA[4], sB[4];
    #pragma unroll
    for (int o = 32; o; o >>= 1) { s += __shfl_xor(s, o, 64); s2 += __shfl_xor(s2, o, 64); }
    const int lane = threadIdx.x & 63, wid = threadIdx.x >> 6;
    if (lane == 0) { sA[wid] = s; sB[wid] = s2; }
    __syncthreads();
    s = sA[0] + sA[1] + sA[2] + sA[3];
    s2 = sB[0] + sB[1] + sB[2] + sB[3];
    const float mu = s / D;
    const float rstd = rsqrtf(fmaxf(s2 / D - mu * mu, 0.f) + 1e-5f);
    unsigned short* orow = out + (long long)row * ldo;
    for (int j = threadIdx.x; j < ldo; j += 256) {
        float v = (j < D) ? (hr[j] - mu) * rstd * g[j] + b[j] : 0.f;
        orow[j] = f2bf(v);
    }
}

// ---------------- causal row softmax (scores f32 -> P bf16, zero-fill to tile edge) ----
__global__ __launch_bounds__(256) void softmax_k(const float* __restrict__ scores,
                                                 unsigned short* __restrict__ P,
                                                 float scale) {
    const int i = blockIdx.x;
    const long long rb = ((long long)blockIdx.y * 1024 + i) * 1024;
    const float* srow = scores + rb;
    unsigned short* prow = P + rb;
    const int n = i + 1;
    float mx = -3.4e38f;
    for (int j = threadIdx.x; j < n; j += 256) mx = fmaxf(mx, srow[j]);
    __shared__ float sA[4], sB[4];
    #pragma unroll
    for (int o = 32; o; o >>= 1) mx = fmaxf(mx, __shfl_xor(mx, o, 64));
    const int lane = threadIdx.x & 63, wid = threadIdx.x >> 6;
    if (lane == 0) sA[wid] = mx;
    __syncthreads();
    mx = fmaxf(fmaxf(sA[0], sA[1]), fmaxf(sA[2], sA[3])) * scale;
    float sum = 0.f;
    for (int j = threadIdx.x; j < n; j += 256) sum += __expf(srow[j] * scale - mx);
    #pragma unroll
    for (int o = 32; o; o >>= 1) sum += __shfl_xor(sum, o, 64);
    if (lane == 0) sB[wid] = sum;
    __syncthreads();
    const float inv = 1.f / (sB[0] + sB[1] + sB[2] + sB[3]);
    const int nz = ((i >> 7) + 1) << 7;   // zero up to the 128-tile edge (PV K-limit)
    for (int j = threadIdx.x; j < nz; j += 256) {
        float p = (j < n) ? __expf(srow[j] * scale - mx) * inv : 0.f;
        prow[j] = f2bf(p);
    }
}

// ---------------- generic bf16 MFMA GEMM, 128x128 tile, BK=32 ----------------
// ABF: A is bf16 (else f32, converted in staging). BNT: B is [N][K] (else [K][N]).
// EPI: 0 store f32 (+bias), 1 relu->bf16 w/ perm zero-kill, 2 accumulate f32 (+bias),
//      3 gather-scatter accumulate via perm (+bias).
// GATHER: A rows via perm.  CAUSAL: 1 skip upper tiles, 2 limit K to diag tile.
#define BM 128
#define BN 128
#define BK 32
template<bool ABF, bool BNT, int EPI, bool GATHER, int CAUSAL>
__global__ __launch_bounds__(256) void gemm_k(
    const void* __restrict__ Ap_, int lda, long long zsA,
    const float* __restrict__ Bp_, int ldb, long long zsB,
    void* __restrict__ Cp_, int ldc, long long zsC,
    const float* __restrict__ bias_, long long zsBias,
    const int* __restrict__ perm_, const int* __restrict__ pcnt,
    int N, int K) {
    const int z = blockIdx.z;
    const int gm0 = blockIdx.y * BM;
    const int n0 = blockIdx.x * BN;
    if (pcnt && gm0 >= pcnt[z]) return;
    if (CAUSAL == 1 && n0 >= gm0 + BM) return;

    const unsigned short* A16 = ABF ? (const unsigned short*)Ap_ + (long long)z * zsA : nullptr;
    const float* A32 = ABF ? nullptr : (const float*)Ap_ + (long long)z * zsA;
    const float* Bp = Bp_ + (long long)z * zsB;
    const float* bias = bias_ ? bias_ + (long long)z * zsBias : nullptr;
    const int* perm = perm_ ? perm_ + (long long)z * 1024 : nullptr;
    void* Cp = (EPI == 1) ? (void*)((unsigned short*)Cp_ + (long long)z * zsC)
                          : (void*)((float*)Cp_ + (long long)z * zsC);

    __shared__ unsigned short Al[BM][BK + 8];
    __shared__ unsigned short Bl[BN][BK + 8];

    const int tid = threadIdx.x;
    const int lane = tid & 63;
    const int wid = tid >> 6;
    const int wr = wid >> 1, wc = wid & 1;

    f32x4 acc[4][4] = {};

    int kEnd = K;
    if (CAUSAL == 2) kEnd = (K < gm0 + BM) ? K : (gm0 + BM);

    const int arow = tid >> 1;
    const int aseg = (tid & 1) * 16;
    const int bkk = tid >> 3;
    const int bnn = (tid & 7) * 16;

    for (int k0 = 0; k0 < kEnd; k0 += BK) {
        // ---- stage A tile: Al[row][k] ----
        {
            const int kb = k0 + aseg;
            const int srow = gm0 + arow;
            const int asrc = GATHER ? perm[srow] : srow;
            unsigned short* dst = &Al[arow][aseg];
            if (ABF) {
                const unsigned short* As = A16 + (long long)asrc * lda;
                if (asrc >= 0 && kb + 16 <= K) {
                    ((short8*)dst)[0] = ((const short8*)(As + kb))[0];
                    ((short8*)dst)[1] = ((const short8*)(As + kb))[1];
                } else {
                    #pragma unroll
                    for (int j = 0; j < 16; ++j)
                        dst[j] = (asrc >= 0 && kb + j < K) ? As[kb + j] : (unsigned short)0;
                }
            } else {
                const float* As = A32 + (long long)asrc * lda;
                if (asrc >= 0 && kb + 16 <= K && (((uintptr_t)As & 15) == 0)) {
                    #pragma unroll
                    for (int q = 0; q < 4; ++q) {
                        f32x4 v = *(const f32x4*)(As + kb + q * 4);
                        #pragma unroll
                        for (int j = 0; j < 4; ++j) dst[q * 4 + j] = f2bf(v[j]);
                    }
                } else {
                    #pragma unroll
                    for (int j = 0; j < 16; ++j)
                        dst[j] = f2bf((asrc >= 0 && kb + j < K) ? As[kb + j] : 0.f);
                }
            }
        }
        // ---- stage B tile: Bl[col][k] ----
        if (BNT) {
            const int kb = k0 + aseg;
            const int gn = n0 + arow;
            unsigned short* dst = &Bl[arow][aseg];
            const float* Bs = Bp + (long long)gn * ldb;
            if (gn < N && kb + 16 <= K && (((uintptr_t)Bs & 15) == 0)) {
                #pragma unroll
                for (int q = 0; q < 4; ++q) {
                    f32x4 v = *(const f32x4*)(Bs + kb + q * 4);
                    #pragma unroll
                    for (int j = 0; j < 4; ++j) dst[q * 4 + j] = f2bf(v[j]);
                }
            } else {
                #pragma unroll
                for (int j = 0; j < 16; ++j)
                    dst[j] = f2bf((gn < N && kb + j < K) ? Bs[kb + j] : 0.f);
            }
        } else {
            const int k = k0 + bkk;
            const float* Bs = Bp + (long long)k * ldb + n0 + bnn;
            if (k < K && n0 + bnn + 16 <= N && (((uintptr_t)Bs & 15) == 0)) {
                #pragma unroll
                for (int q = 0; q < 4; ++q) {
                    f32x4 v = *(const f32x4*)(Bs + q * 4);
                    #pragma unroll
                    for (int j = 0; j < 4; ++j) Bl[bnn + q * 4 + j][bkk] = f2bf(v[j]);
                }
            } else {
                #pragma unroll
                for (int j = 0; j < 16; ++j) {
                    float v = (k < K && (n0 + bnn + j) < N) ? Bs[j] : 0.f;
                    Bl[bnn + j][bkk] = f2bf(v);
                }
            }
        }
        __syncthreads();
        // ---- MFMA ----
        const int l15 = lane & 15;
        const int kfr = (lane >> 4) * 8;
        short8 af[4], bfv[4];
        #pragma unroll
        for (int m = 0; m < 4; ++m) af[m] = *(const short8*)&Al[wr * 64 + m * 16 + l15][kfr];
        #pragma unroll
        for (int n = 0; n < 4; ++n) bfv[n] = *(const short8*)&Bl[wc * 64 + n * 16 + l15][kfr];
        #pragma unroll
        for (int m = 0; m < 4; ++m)
            #pragma unroll
            for (int n = 0; n < 4; ++n)
                acc[m][n] = __builtin_amdgcn_mfma_f32_16x16x32_bf16(af[m], bfv[n], acc[m][n], 0, 0, 0);
        __syncthreads();
    }

    // ---- epilogue ----
    {
        const int l15 = lane & 15;
        const int lq = (lane >> 4) * 4;
        #pragma unroll
        for (int m = 0; m < 4; ++m) {
            const int trow = wr * 64 + m * 16 + lq;
            #pragma unroll
            for (int n = 0; n < 4; ++n) {
                const int col = n0 + wc * 64 + n * 16 + l15;
                if (col >= N) continue;
                const float bv = bias ? bias[col] : 0.f;
                #pragma unroll
                for (int r = 0; r < 4; ++r) {
                    const int grow = gm0 + trow + r;
                    const float v = acc[m][n][r] + bv;
                    if (EPI == 0) {
                        ((float*)Cp)[(long long)grow * ldc + col] = v;
                    } else if (EPI == 1) {
                        const int tok = perm[grow];
                        ((unsigned short*)Cp)[(long long)grow * ldc + col] =
                            (tok >= 0) ? f2bf(fmaxf(v, 0.f)) : (unsigned short)0;
                    } else if (EPI == 2) {
                        ((float*)Cp)[(long long)grow * ldc + col] += v;
                    } else {
                        const int tok = perm[grow];
                        if (tok >= 0) ((float*)Cp)[(long long)tok * ldc + col] += v;
                    }
                }
            }
        }
    }
}

extern "C" void kernel_launch(void* const* d_in, const int* in_sizes, int n_in,
                              void* d_out, int out_size, void* d_ws, size_t ws_size,
                              hipStream_t stream) {
    const float* x     = (const float*)d_in[0];
    const float* ln1_g = (const float*)d_in[1];
    const float* ln1_b = (const float*)d_in[2];
    const float* wqkv  = (const float*)d_in[3];
    const float* bqkv  = (const float*)d_in[4];
    const float* wo    = (const float*)d_in[5];
    const float* bo    = (const float*)d_in[6];
    const float* ln2_g = (const float*)d_in[7];
    const float* ln2_b = (const float*)d_in[8];
    const float* w1    = (const float*)d_in[9];
    const float* b1    = (const float*)d_in[10];
    const float* w2    = (const float*)d_in[11];
    const float* b2    = (const float*)d_in[12];

    float* h = (float*)d_out;   // residual stream lives in d_out (f32)

    char* w = (char*)d_ws;
    unsigned short* lnA = (unsigned short*)w; w += (size_t)S_LEN * LDAP * 2;        // 2.82 MB
    float* qkvb = (float*)w;                  w += (size_t)S_LEN * TD * 4;          // 16.6 MB
    float* scores = (float*)w;                w += (size_t)NHEAD * S_LEN * S_LEN * 4; // 33.6 MB
    unsigned short* Pbuf = (unsigned short*)w; w += (size_t)NHEAD * S_LEN * S_LEN * 2; // 16.8 MB
    float* obuf = (float*)w;                  w += (size_t)S_LEN * DMODEL * 4;      // 5.5 MB
    unsigned short* hid = (unsigned short*)w; w += (size_t)4096 * DFFN * 2;         // 22.2 MB
    int* perm = (int*)w;                      w += 4096 * 4;
    int* pcnt = (int*)w;                      w += 64;

    hipMemcpyAsync(h, x, (size_t)S_LEN * DMODEL * 4, hipMemcpyDeviceToDevice, stream);
    route_k<<<1, 256, 0, stream>>>(x, perm, pcnt);

    const float scale = 1.0f / 13.0f;   // 1/sqrt(169)

    for (int l = 0; l < NLAYER; ++l) {
        const float* wqkv_l = wqkv + (long long)l * DMODEL * TD;
        const float* wo_l   = wo   + (long long)l * DMODEL * DMODEL;
        const float* w1_l   = w1   + (long long)l * 4 * DMODEL * DFFN;
        const float* w2_l   = w2   + (long long)l * 4 * DFFN * DMODEL;

        // LN1 -> bf16
        ln_k<<<1024, 256, 0, stream>>>(h, ln1_g + l * DMODEL, ln1_b + l * DMODEL, lnA, DMODEL, LDAP);
        // QKV = lnA @ wqkv + bqkv   [1024 x 4056]
        gemm_k<true, false, 0, false, 0><<<dim3(32, 8, 1), 256, 0, stream>>>(
            lnA, LDAP, 0, wqkv_l, TD, 0, qkvb, TD, 0,
            bqkv + l * TD, 0, nullptr, nullptr, TD, DMODEL);
        // scores = q @ k^T  (per head, causal tiles only)
        gemm_k<false, true, 0, false, 1><<<dim3(8, 8, 8), 256, 0, stream>>>(
            qkvb, TD, HDIM, qkvb + DMODEL, TD, HDIM, scores, 1024, 1024 * 1024,
            nullptr, 0, nullptr, nullptr, 1024, HDIM);
        // P = softmax(scale * scores) causal, bf16
        softmax_k<<<dim3(1024, NHEAD), 256, 0, stream>>>(scores, Pbuf, scale);
        // o = P @ v  (per head, K limited to diagonal tile)
        gemm_k<true, false, 0, false, 2><<<dim3(2, 8, 8), 256, 0, stream>>>(
            Pbuf, 1024, 1024 * 1024, qkvb + 2 * DMODEL, TD, HDIM, obuf, DMODEL, HDIM,
            nullptr, 0, nullptr, nullptr, HDIM, 1024);
        // h += o @ wo + bo
        gemm_k<false, false, 2, false, 0><<<dim3(11, 8, 1), 256, 0, stream>>>(
            obuf, DMODEL, 0, wo_l, DMODEL, 0, h, DMODEL, 0,
            bo + l * DMODEL, 0, nullptr, nullptr, DMODEL, DMODEL);
        // LN2 -> bf16
        ln_k<<<1024, 256, 0, stream>>>(h, ln2_g + l * DMODEL, ln2_b + l * DMODEL, lnA, DMODEL, LDAP);
        // hid = relu(gather(lnA) @ w1[e] + b1[e])  -> bf16, per expert
        gemm_k<true, false, 1, true, 0><<<dim3(22, 8, 4), 256, 0, stream>>>(
            lnA, LDAP, 0, w1_l, DFFN, (long long)DMODEL * DFFN,
            hid, DFFN, (long long)1024 * DFFN,
            b1 + (long long)l * 4 * DFFN, DFFN, perm, pcnt, DFFN, DMODEL);
        // h[tok] += hid @ w2[e] + b2[e]  (scatter via perm)
        gemm_k<true, false, 3, false, 0><<<dim3(11, 8, 4), 256, 0, stream>>>(
            hid, DFFN, (long long)1024 * DFFN, w2_l, DMODEL, (long long)DFFN * DMODEL,
            h, DMODEL, 0,
            b2 + (long long)l * 4 * DMODEL, DMODEL, perm, pcnt, DMODEL, DFFN);
    }
}

// Round 2
// 3524.974 us; speedup vs baseline: 1.6403x; 1.6403x over previous
//
#include <hip/hip_runtime.h>
#include <hip/hip_bf16.h>
#include <cstdint>

#define S_LEN 1024
#define DMODEL 1352
#define TD 4056
#define DFFN 2704
#define NHEAD 8
#define HDIM 169
#define NLAYER 7
#define LDAP 1376   // 1352 -> 43*32
#define KP2 2720    // 2704 -> 85*32

typedef __attribute__((ext_vector_type(8))) short short8;
typedef __attribute__((ext_vector_type(4))) float f32x4;
typedef __attribute__((ext_vector_type(2))) unsigned short us2;

__device__ __forceinline__ unsigned short f2bf(float f) {
    union { float f; unsigned int u; } c; c.f = f;
    unsigned int r = (c.u + 0x7fffu + ((c.u >> 16) & 1u)) >> 16;
    return (unsigned short)r;
}

__device__ __forceinline__ void g2l16(const void* g, void* l) {
    __builtin_amdgcn_global_load_lds((__attribute__((address_space(1))) void*)g,
                                     (__attribute__((address_space(3))) void*)l,
                                     16, 0, 0);
}

// ---------------- routing: per-expert token compaction (1 block) ----------------
__global__ __launch_bounds__(256) void route_k(const float* __restrict__ x,
                                               int* __restrict__ perm,
                                               int* __restrict__ pcnt) {
    const int tid = threadIdx.x;
    const int lane = tid & 63;
    const int w = tid >> 6;
    for (int i = tid; i < 4096; i += 256) perm[i] = -1;
    __syncthreads();
    int base = 0;
    for (int c = 0; c < 16; ++c) {
        const int t = c * 64 + lane;
        const float* xr = x + (long long)t * DMODEL;
        float best = xr[0]; int bi = 0;
        #pragma unroll
        for (int j = 1; j < 16; ++j) { float v = xr[j]; if (v > best) { best = v; bi = j; } }
        const bool match = ((bi & 3) == w);
        unsigned long long mb = __ballot(match);
        int pos = __popcll(mb & ((1ull << lane) - 1ull));
        if (match) perm[w * 1024 + base + pos] = t;
        base += __popcll(mb);
    }
    if (lane == 0) pcnt[w] = (base + 127) & ~127;
}

// ---------------- layernorm -> bf16 (zero-padded to ldo) ----------------
__global__ __launch_bounds__(256) void ln_k(const float* __restrict__ h,
                                            const float* __restrict__ g,
                                            const float* __restrict__ b,
                                            unsigned short* __restrict__ out,
                                            int D, int ldo) {
    const int row = blockIdx.x;
    const float* hr = h + (long long)row * D;
    float s = 0.f, s2 = 0.f;
    for (int j = threadIdx.x; j < D; j += 256) { float v = hr[j]; s += v; s2 += v * v; }
    __shared__ float sA[4], sB[4];
    #pragma unroll
    for (int o = 32; o; o >>= 1) { s += __shfl_xor(s, o, 64); s2 += __shfl_xor(s2, o, 64); }
    const int lane = threadIdx.x & 63, wid = threadIdx.x >> 6;
    if (lane == 0) { sA[wid] = s; sB[wid] = s2; }
    __syncthreads();
    s = sA[0] + sA[1] + sA[2] + sA[3];
    s2 = sB[0] + sB[1] + sB[2] + sB[3];
    const float mu = s / D;
    const float rstd = rsqrtf(fmaxf(s2 / D - mu * mu, 0.f) + 1e-5f);
    unsigned short* orow = out + (long long)row * ldo;
    for (int j = threadIdx.x; j < ldo; j += 256) {
        float v = (j < D) ? (hr[j] - mu) * rstd * g[j] + b[j] : 0.f;
        orow[j] = f2bf(v);
    }
}

// ---------------- transpose+convert: f32 [K][N] -> bf16 [N][Kp] (zero pad k>=K) ----
__global__ __launch_bounds__(256) void tconv_k(const float* __restrict__ src,
                                               unsigned short* __restrict__ dst,
                                               int K, int N, int Kp,
                                               long long zsrc, long long zdst) {
    src += (long long)blockIdx.z * zsrc;
    dst += (long long)blockIdx.z * zdst;
    __shared__ float t[32][33];
    const int k0 = blockIdx.x * 32, n0 = blockIdx.y * 32;
    const int tx = threadIdx.x & 31, ty = threadIdx.x >> 5;
    #pragma unroll
    for (int i = 0; i < 4; ++i) {
        int k = k0 + ty + i * 8, n = n0 + tx;
        t[ty + i * 8][tx] = (k < K && n < N) ? src[(long long)k * N + n] : 0.f;
    }
    __syncthreads();
    #pragma unroll
    for (int i = 0; i < 2; ++i) {
        int s = threadIdx.x + i * 256;
        int nr = s >> 4;
        int kp = (s & 15) * 2;
        int n = n0 + nr;
        if (n < N) {
            us2 w; w.x = f2bf(t[kp][nr]); w.y = f2bf(t[kp + 1][nr]);
            *(us2*)&dst[(long long)n * Kp + k0 + kp] = w;
        }
    }
}

// ---------------- causal row softmax (scores f32 -> P bf16) ----------------
__global__ __launch_bounds__(256) void softmax_k(const float* __restrict__ scores,
                                                 unsigned short* __restrict__ P,
                                                 float scale) {
    const int i = blockIdx.x;
    const long long rb = ((long long)blockIdx.y * 1024 + i) * 1024;
    const float* srow = scores + rb;
    unsigned short* prow = P + rb;
    const int n = i + 1;
    float mx = -3.4e38f;
    for (int j = threadIdx.x; j < n; j += 256) mx = fmaxf(mx, srow[j]);
    __shared__ float sA[4], sB[4];
    #pragma unroll
    for (int o = 32; o; o >>= 1) mx = fmaxf(mx, __shfl_xor(mx, o, 64));
    const int lane = threadIdx.x & 63, wid = threadIdx.x >> 6;
    if (lane == 0) sA[wid] = mx;
    __syncthreads();
    mx = fmaxf(fmaxf(sA[0], sA[1]), fmaxf(sA[2], sA[3])) * scale;
    float sum = 0.f;
    for (int j = threadIdx.x; j < n; j += 256) sum += __expf(srow[j] * scale - mx);
    #pragma unroll
    for (int o = 32; o; o >>= 1) sum += __shfl_xor(sum, o, 64);
    if (lane == 0) sB[wid] = sum;
    __syncthreads();
    const float inv = 1.f / (sB[0] + sB[1] + sB[2] + sB[3]);
    const int nz = ((i >> 7) + 1) << 7;
    for (int j = threadIdx.x; j < nz; j += 256) {
        float p = (j < n) ? __expf(srow[j] * scale - mx) * inv : 0.f;
        prow[j] = f2bf(p);
    }
}

// ---------------- old flexible GEMM (kept for scores / PV only) ----------------
// EPI: 0 store f32, 4 store bf16.  CAUSAL: 1 skip upper tiles, 2 K limited to diag.
#define BM 128
#define BN 128
#define BK 32
template<bool ABF, bool BNT, int EPI, int CAUSAL>
__global__ __launch_bounds__(256) void gemm_k(
    const void* __restrict__ Ap_, int lda, long long zsA,
    const float* __restrict__ Bp_, int ldb, long long zsB,
    void* __restrict__ Cp_, int ldc, long long zsC,
    int N, int K) {
    const int z = blockIdx.z;
    const int gm0 = blockIdx.y * BM;
    const int n0 = blockIdx.x * BN;
    if (CAUSAL == 1 && n0 >= gm0 + BM) return;

    const unsigned short* A16 = ABF ? (const unsigned short*)Ap_ + (long long)z * zsA : nullptr;
    const float* A32 = ABF ? nullptr : (const float*)Ap_ + (long long)z * zsA;
    const float* Bp = Bp_ + (long long)z * zsB;
    void* Cp = (EPI == 4) ? (void*)((unsigned short*)Cp_ + (long long)z * zsC)
                          : (void*)((float*)Cp_ + (long long)z * zsC);

    __shared__ unsigned short Al[BM][BK + 8];
    __shared__ unsigned short Bl[BN][BK + 8];

    const int tid = threadIdx.x;
    const int lane = tid & 63;
    const int wid = tid >> 6;
    const int wr = wid >> 1, wc = wid & 1;

    f32x4 acc[4][4] = {};

    int kEnd = K;
    if (CAUSAL == 2) kEnd = (K < gm0 + BM) ? K : (gm0 + BM);

    const int arow = tid >> 1;
    const int aseg = (tid & 1) * 16;
    const int bkk = tid >> 3;
    const int bnn = (tid & 7) * 16;

    for (int k0 = 0; k0 < kEnd; k0 += BK) {
        {
            const int kb = k0 + aseg;
            const int srow = gm0 + arow;
            unsigned short* dst = &Al[arow][aseg];
            if (ABF) {
                const unsigned short* As = A16 + (long long)srow * lda;
                if (kb + 16 <= K) {
                    ((short8*)dst)[0] = ((const short8*)(As + kb))[0];
                    ((short8*)dst)[1] = ((const short8*)(As + kb))[1];
                } else {
                    #pragma unroll
                    for (int j = 0; j < 16; ++j)
                        dst[j] = (kb + j < K) ? As[kb + j] : (unsigned short)0;
                }
            } else {
                const float* As = A32 + (long long)srow * lda;
                if (kb + 16 <= K && (((uintptr_t)As & 15) == 0)) {
                    #pragma unroll
                    for (int q = 0; q < 4; ++q) {
                        f32x4 v = *(const f32x4*)(As + kb + q * 4);
                        #pragma unroll
                        for (int j = 0; j < 4; ++j) dst[q * 4 + j] = f2bf(v[j]);
                    }
                } else {
                    #pragma unroll
                    for (int j = 0; j < 16; ++j)
                        dst[j] = f2bf((kb + j < K) ? As[kb + j] : 0.f);
                }
            }
        }
        if (BNT) {
            const int kb = k0 + aseg;
            const int gn = n0 + arow;
            unsigned short* dst = &Bl[arow][aseg];
            const float* Bs = Bp + (long long)gn * ldb;
            if (gn < N && kb + 16 <= K && (((uintptr_t)Bs & 15) == 0)) {
                #pragma unroll
                for (int q = 0; q < 4; ++q) {
                    f32x4 v = *(const f32x4*)(Bs + kb + q * 4);
                    #pragma unroll
                    for (int j = 0; j < 4; ++j) dst[q * 4 + j] = f2bf(v[j]);
                }
            } else {
                #pragma unroll
                for (int j = 0; j < 16; ++j)
                    dst[j] = f2bf((gn < N && kb + j < K) ? Bs[kb + j] : 0.f);
            }
        } else {
            const int k = k0 + bkk;
            const float* Bs = Bp + (long long)k * ldb + n0 + bnn;
            if (k < K && n0 + bnn + 16 <= N && (((uintptr_t)Bs & 15) == 0)) {
                #pragma unroll
                for (int q = 0; q < 4; ++q) {
                    f32x4 v = *(const f32x4*)(Bs + q * 4);
                    #pragma unroll
                    for (int j = 0; j < 4; ++j) Bl[bnn + q * 4 + j][bkk] = f2bf(v[j]);
                }
            } else {
                #pragma unroll
                for (int j = 0; j < 16; ++j) {
                    float v = (k < K && (n0 + bnn + j) < N) ? Bs[j] : 0.f;
                    Bl[bnn + j][bkk] = f2bf(v);
                }
            }
        }
        __syncthreads();
        const int l15 = lane & 15;
        const int kfr = (lane >> 4) * 8;
        short8 af[4], bfv[4];
        #pragma unroll
        for (int m = 0; m < 4; ++m) af[m] = *(const short8*)&Al[wr * 64 + m * 16 + l15][kfr];
        #pragma unroll
        for (int n = 0; n < 4; ++n) bfv[n] = *(const short8*)&Bl[wc * 64 + n * 16 + l15][kfr];
        #pragma unroll
        for (int m = 0; m < 4; ++m)
            #pragma unroll
            for (int n = 0; n < 4; ++n)
                acc[m][n] = __builtin_amdgcn_mfma_f32_16x16x32_bf16(af[m], bfv[n], acc[m][n], 0, 0, 0);
        __syncthreads();
    }

    {
        const int l15 = lane & 15;
        const int lq = (lane >> 4) * 4;
        #pragma unroll
        for (int m = 0; m < 4; ++m) {
            const int trow = wr * 64 + m * 16 + lq;
            #pragma unroll
            for (int n = 0; n < 4; ++n) {
                const int col = n0 + wc * 64 + n * 16 + l15;
                if (col >= N) continue;
                #pragma unroll
                for (int r = 0; r < 4; ++r) {
                    const int grow = gm0 + trow + r;
                    const float v = acc[m][n][r];
                    if (EPI == 0) ((float*)Cp)[(long long)grow * ldc + col] = v;
                    else          ((unsigned short*)Cp)[(long long)grow * ldc + col] = f2bf(v);
                }
            }
        }
    }
}

// ---------------- fast GEMM: bf16 A [M][Kp], bf16 B^T [N][Kp], global_load_lds,
// 2-phase double-buffered, 128x128x32.
// EPI: 0 store f32 + bias, 1 relu->bf16 + zero-kill (perm), 2 accumulate f32 + bias,
//      3 scatter-add via perm + bias.  GATHER: A rows via perm.
template<int EPI, bool GATHER>
__global__ __launch_bounds__(256) void gemm2_k(
    const unsigned short* __restrict__ A_, int lda, long long zsA,
    const unsigned short* __restrict__ B_, int ldb, long long zsB,
    void* __restrict__ C_, int ldc, long long zsC,
    const float* __restrict__ bias_, long long zsBias,
    const int* __restrict__ perm_, const int* __restrict__ pcnt,
    int N, int Kp) {
    const int z = blockIdx.z;
    const int gm0 = blockIdx.y * 128;
    const int n0 = blockIdx.x * 128;
    if (pcnt && gm0 >= pcnt[z]) return;

    const unsigned short* A = A_ + (long long)z * zsA;
    const unsigned short* B = B_ + (long long)z * zsB;
    const float* bias = bias_ ? bias_ + (long long)z * zsBias : nullptr;
    const int* perm = perm_ ? perm_ + (long long)z * 1024 : nullptr;
    void* C = (EPI == 1) ? (void*)((unsigned short*)C_ + (long long)z * zsC)
                         : (void*)((float*)C_ + (long long)z * zsC);

    __shared__ unsigned short Al[2][128 * 32];
    __shared__ unsigned short Bl[2][128 * 32];

    const int tid = threadIdx.x, lane = tid & 63, wid = tid >> 6;
    const int wr = wid >> 1, wc = wid & 1;
    const int c0 = wid * 2;
    const int lrow = lane >> 2;
    const int lseg = (lane & 3) * 8;

    const unsigned short* gA[2];
    const unsigned short* gB[2];
    #pragma unroll
    for (int i = 0; i < 2; ++i) {
        const int row = (c0 + i) * 16 + lrow;
        int ar = gm0 + row;
        if (GATHER) { const int p = perm[ar]; ar = (p < 0) ? 0 : p; }
        gA[i] = A + (long long)ar * lda + lseg;
        gB[i] = B + (long long)(n0 + row) * ldb + lseg;
    }

    f32x4 acc[4][4] = {};
    const int nt = Kp >> 5;

    #pragma unroll
    for (int i = 0; i < 2; ++i) {
        g2l16(gA[i], &Al[0][(c0 + i) * 512]);
        g2l16(gB[i], &Bl[0][(c0 + i) * 512]);
    }
    __syncthreads();

    int cur = 0;
    for (int t = 0; t < nt; ++t) {
        if (t + 1 < nt) {
            const int ko = (t + 1) * 32;
            #pragma unroll
            for (int i = 0; i < 2; ++i) {
                g2l16(gA[i] + ko, &Al[cur ^ 1][(c0 + i) * 512]);
                g2l16(gB[i] + ko, &Bl[cur ^ 1][(c0 + i) * 512]);
            }
        }
        const int l15 = lane & 15, kfr = (lane >> 4) * 8;
        short8 af[4], bfv[4];
        #pragma unroll
        for (int m = 0; m < 4; ++m)
            af[m] = *(const short8*)&Al[cur][(wr * 64 + m * 16 + l15) * 32 + kfr];
        #pragma unroll
        for (int n = 0; n < 4; ++n)
            bfv[n] = *(const short8*)&Bl[cur][(wc * 64 + n * 16 + l15) * 32 + kfr];
        #pragma unroll
        for (int m = 0; m < 4; ++m)
            #pragma unroll
            for (int n = 0; n < 4; ++n)
                acc[m][n] = __builtin_amdgcn_mfma_f32_16x16x32_bf16(af[m], bfv[n], acc[m][n], 0, 0, 0);
        __syncthreads();
        cur ^= 1;
    }

    const int l15 = lane & 15, lq = (lane >> 4) * 4;
    #pragma unroll
    for (int m = 0; m < 4; ++m) {
        const int trow = wr * 64 + m * 16 + lq;
        #pragma unroll
        for (int n = 0; n < 4; ++n) {
            const int col = n0 + wc * 64 + n * 16 + l15;
            if (col >= N) continue;
            const float bv = bias ? bias[col] : 0.f;
            #pragma unroll
            for (int r = 0; r < 4; ++r) {
                const int grow = gm0 + trow + r;
                const float v = acc[m][n][r] + bv;
                if (EPI == 0) {
                    ((float*)C)[(long long)grow * ldc + col] = v;
                } else if (EPI == 1) {
                    const int tok = perm[grow];
                    ((unsigned short*)C)[(long long)grow * ldc + col] =
                        (tok >= 0) ? f2bf(fmaxf(v, 0.f)) : (unsigned short)0;
                } else if (EPI == 2) {
                    ((float*)C)[(long long)grow * ldc + col] += v;
                } else {
                    const int tok = perm[grow];
                    if (tok >= 0) ((float*)C)[(long long)tok * ldc + col] += v;
                }
            }
        }
    }
}

extern "C" void kernel_launch(void* const* d_in, const int* in_sizes, int n_in,
                              void* d_out, int out_size, void* d_ws, size_t ws_size,
                              hipStream_t stream) {
    const float* x     = (const float*)d_in[0];
    const float* ln1_g = (const float*)d_in[1];
    const float* ln1_b = (const float*)d_in[2];
    const float* wqkv  = (const float*)d_in[3];
    const float* bqkv  = (const float*)d_in[4];
    const float* wo    = (const float*)d_in[5];
    const float* bo    = (const float*)d_in[6];
    const float* ln2_g = (const float*)d_in[7];
    const float* ln2_b = (const float*)d_in[8];
    const float* w1    = (const float*)d_in[9];
    const float* b1    = (const float*)d_in[10];
    const float* w2    = (const float*)d_in[11];
    const float* b2    = (const float*)d_in[12];

    float* h = (float*)d_out;

    char* w = (char*)d_ws;
    auto alloc = [&](size_t bytes) { void* p = w; w += (bytes + 255) & ~255ull; return p; };
    unsigned short* lnA   = (unsigned short*)alloc((size_t)S_LEN * LDAP * 2);     // 2.82 MB
    float*          qkvb  = (float*)alloc((size_t)S_LEN * TD * 4);                // 16.6 MB
    unsigned short* obufb = (unsigned short*)alloc((size_t)S_LEN * LDAP * 2);     // 2.82 MB
    unsigned short* hid   = (unsigned short*)alloc((size_t)4096 * KP2 * 2);       // 22.3 MB
    unsigned short* wqkvT = (unsigned short*)alloc((size_t)4096 * LDAP * 2);      // 11.3 MB
    unsigned short* woT   = (unsigned short*)alloc((size_t)1408 * LDAP * 2);      // 3.87 MB
    char*           U     = (char*)alloc((size_t)61700000);                       // union region
    int* perm = (int*)alloc(4096 * 4);
    int* pcnt = (int*)alloc(64);

    float*          scores = (float*)U;                                   // [0, 33.55M)
    unsigned short* Pbuf   = (unsigned short*)(U + (size_t)NHEAD * 1024 * 1024 * 4);
    unsigned short* w1T    = (unsigned short*)U;                          // [0, 31.0M)
    unsigned short* w2T    = (unsigned short*)(U + (size_t)4 * 2816 * LDAP * 2);

    hipMemcpyAsync(h, x, (size_t)S_LEN * DMODEL * 4, hipMemcpyDeviceToDevice, stream);
    hipMemsetAsync(hid, 0, (size_t)4096 * KP2 * 2, stream);
    hipMemsetAsync(obufb, 0, (size_t)S_LEN * LDAP * 2, stream);
    route_k<<<1, 256, 0, stream>>>(x, perm, pcnt);

    const float scale = 1.0f / 13.0f;

    for (int l = 0; l < NLAYER; ++l) {
        const float* wqkv_l = wqkv + (long long)l * DMODEL * TD;
        const float* wo_l   = wo   + (long long)l * DMODEL * DMODEL;
        const float* w1_l   = w1   + (long long)l * 4 * DMODEL * DFFN;
        const float* w2_l   = w2   + (long long)l * 4 * DFFN * DMODEL;

        // transpose+convert attention weights for this layer
        tconv_k<<<dim3(43, 127, 1), 256, 0, stream>>>(wqkv_l, wqkvT, DMODEL, TD, LDAP, 0, 0);
        tconv_k<<<dim3(43, 43, 1), 256, 0, stream>>>(wo_l, woT, DMODEL, DMODEL, LDAP, 0, 0);

        // LN1 -> bf16
        ln_k<<<1024, 256, 0, stream>>>(h, ln1_g + l * DMODEL, ln1_b + l * DMODEL, lnA, DMODEL, LDAP);
        // QKV = lnA @ wqkv + bqkv -> f32 [1024][4056]
        gemm2_k<0, false><<<dim3(32, 8, 1), 256, 0, stream>>>(
            lnA, LDAP, 0, wqkvT, LDAP, 0, qkvb, TD, 0,
            bqkv + l * TD, 0, nullptr, nullptr, TD, LDAP);
        // scores = q @ k^T (per head, causal tiles)
        gemm_k<false, true, 0, 1><<<dim3(8, 8, 8), 256, 0, stream>>>(
            qkvb, TD, HDIM, qkvb + DMODEL, TD, HDIM, scores, 1024, 1024 * 1024,
            1024, HDIM);
        softmax_k<<<dim3(1024, NHEAD), 256, 0, stream>>>(scores, Pbuf, scale);
        // o = P @ v -> bf16 obufb [1024][1376]
        gemm_k<true, false, 4, 2><<<dim3(2, 8, 8), 256, 0, stream>>>(
            Pbuf, 1024, 1024 * 1024, qkvb + 2 * DMODEL, TD, HDIM, obufb, LDAP, HDIM,
            HDIM, 1024);
        // h += o @ wo + bo
        gemm2_k<2, false><<<dim3(11, 8, 1), 256, 0, stream>>>(
            obufb, LDAP, 0, woT, LDAP, 0, h, DMODEL, 0,
            bo + l * DMODEL, 0, nullptr, nullptr, DMODEL, LDAP);

        // transpose+convert MoE weights (aliases scores/Pbuf region; both dead now)
        tconv_k<<<dim3(43, 85, 4), 256, 0, stream>>>(
            w1_l, w1T, DMODEL, DFFN, LDAP, (long long)DMODEL * DFFN, (long long)2816 * LDAP);
        tconv_k<<<dim3(85, 43, 4), 256, 0, stream>>>(
            w2_l, w2T, DFFN, DMODEL, KP2, (long long)DFFN * DMODEL, (long long)1408 * KP2);

        // LN2 -> bf16
        ln_k<<<1024, 256, 0, stream>>>(h, ln2_g + l * DMODEL, ln2_b + l * DMODEL, lnA, DMODEL, LDAP);
        // hid = relu(gather(lnA) @ w1[e] + b1[e]) -> bf16
        gemm2_k<1, true><<<dim3(22, 8, 4), 256, 0, stream>>>(
            lnA, LDAP, 0, w1T, LDAP, (long long)2816 * LDAP,
            hid, KP2, (long long)1024 * KP2,
            b1 + (long long)l * 4 * DFFN, DFFN, perm, pcnt, DFFN, LDAP);
        // h[tok] += hid @ w2[e] + b2[e]
        gemm2_k<3, false><<<dim3(11, 8, 4), 256, 0, stream>>>(
            hid, KP2, (long long)1024 * KP2, w2T, KP2, (long long)1408 * KP2,
            h, DMODEL, 0,
            b2 + (long long)l * 4 * DMODEL, DMODEL, perm, pcnt, DMODEL, KP2);
    }
}

// Round 4
// 2748.046 us; speedup vs baseline: 2.1041x; 1.2827x over previous
//
#include <hip/hip_runtime.h>
#include <hip/hip_bf16.h>
#include <cstdint>

#define S_LEN 1024
#define DMODEL 1352
#define TD 4056
#define DFFN 2704
#define NHEAD 8
#define HDIM 169
#define NLAYER 7
#define LDAP 1376   // 1352 -> 43*32
#define KP2 2720    // 2704 -> 85*32
#define QS 1536     // 8 heads * 192
#define HP 192      // head dim padded to 6*32

typedef __attribute__((ext_vector_type(8))) short short8;
typedef __attribute__((ext_vector_type(4))) float f32x4;
typedef __attribute__((ext_vector_type(2))) unsigned short us2;
typedef __attribute__((ext_vector_type(4))) unsigned short us4;

__device__ __forceinline__ unsigned short f2bf(float f) {
    union { float f; unsigned int u; } c; c.f = f;
    unsigned int r = (c.u + 0x7fffu + ((c.u >> 16) & 1u)) >> 16;
    return (unsigned short)r;
}

__device__ __forceinline__ void g2l16(const void* g, void* l) {
    __builtin_amdgcn_global_load_lds((__attribute__((address_space(1))) void*)g,
                                     (__attribute__((address_space(3))) void*)l,
                                     16, 0, 0);
}

// ---------------- routing ----------------
__global__ __launch_bounds__(256) void route_k(const float* __restrict__ x,
                                               int* __restrict__ perm,
                                               int* __restrict__ pcnt) {
    const int tid = threadIdx.x;
    const int lane = tid & 63;
    const int w = tid >> 6;
    for (int i = tid; i < 4096; i += 256) perm[i] = -1;
    __syncthreads();
    int base = 0;
    for (int c = 0; c < 16; ++c) {
        const int t = c * 64 + lane;
        const float* xr = x + (long long)t * DMODEL;
        float best = xr[0]; int bi = 0;
        #pragma unroll
        for (int j = 1; j < 16; ++j) { float v = xr[j]; if (v > best) { best = v; bi = j; } }
        const bool match = ((bi & 3) == w);
        unsigned long long mb = __ballot(match);
        int pos = __popcll(mb & ((1ull << lane) - 1ull));
        if (match) perm[w * 1024 + base + pos] = t;
        base += __popcll(mb);
    }
    if (lane == 0) pcnt[w] = (base + 127) & ~127;
}

// ---------------- layernorm -> bf16 ----------------
__global__ __launch_bounds__(256) void ln_k(const float* __restrict__ h,
                                            const float* __restrict__ g,
                                            const float* __restrict__ b,
                                            unsigned short* __restrict__ out,
                                            int D, int ldo) {
    const int row = blockIdx.x;
    const float* hr = h + (long long)row * D;
    float s = 0.f, s2 = 0.f;
    for (int j = threadIdx.x; j < D; j += 256) { float v = hr[j]; s += v; s2 += v * v; }
    __shared__ float sA[4], sB[4];
    #pragma unroll
    for (int o = 32; o; o >>= 1) { s += __shfl_xor(s, o, 64); s2 += __shfl_xor(s2, o, 64); }
    const int lane = threadIdx.x & 63, wid = threadIdx.x >> 6;
    if (lane == 0) { sA[wid] = s; sB[wid] = s2; }
    __syncthreads();
    s = sA[0] + sA[1] + sA[2] + sA[3];
    s2 = sB[0] + sB[1] + sB[2] + sB[3];
    const float mu = s / D;
    const float rstd = rsqrtf(fmaxf(s2 / D - mu * mu, 0.f) + 1e-5f);
    unsigned short* orow = out + (long long)row * ldo;
    for (int j = threadIdx.x; j < ldo; j += 256) {
        float v = (j < D) ? (hr[j] - mu) * rstd * g[j] + b[j] : 0.f;
        orow[j] = f2bf(v);
    }
}

// ---------------- transpose+convert: f32 [K][N] -> bf16 [N][Kp] ----------------
__global__ __launch_bounds__(256) void tconv_k(const float* __restrict__ src,
                                               unsigned short* __restrict__ dst,
                                               int K, int N, int Kp,
                                               long long zsrc, long long zdst) {
    src += (long long)blockIdx.z * zsrc;
    dst += (long long)blockIdx.z * zdst;
    __shared__ float t[32][33];
    const int k0 = blockIdx.x * 32, n0 = blockIdx.y * 32;
    const int tx = threadIdx.x & 31, ty = threadIdx.x >> 5;
    #pragma unroll
    for (int i = 0; i < 4; ++i) {
        int k = k0 + ty + i * 8, n = n0 + tx;
        t[ty + i * 8][tx] = (k < K && n < N) ? src[(long long)k * N + n] : 0.f;
    }
    __syncthreads();
    #pragma unroll
    for (int i = 0; i < 2; ++i) {
        int s = threadIdx.x + i * 256;
        int nr = s >> 4;
        int kp = (s & 15) * 2;
        int n = n0 + nr;
        if (n < N) {
            us2 w; w.x = f2bf(t[kp][nr]); w.y = f2bf(t[kp + 1][nr]);
            *(us2*)&dst[(long long)n * Kp + k0 + kp] = w;
        }
    }
}

// ---------------- causal row softmax (scores f32 -> P bf16) ----------------
__global__ __launch_bounds__(256) void softmax_k(const float* __restrict__ scores,
                                                 unsigned short* __restrict__ P,
                                                 float scale) {
    const int i = blockIdx.x;
    const long long rb = ((long long)blockIdx.y * 1024 + i) * 1024;
    const float* srow = scores + rb;
    unsigned short* prow = P + rb;
    const int n = i + 1;
    float mx = -3.4e38f;
    for (int j = threadIdx.x; j < n; j += 256) mx = fmaxf(mx, srow[j]);
    __shared__ float sA[4], sB[4];
    #pragma unroll
    for (int o = 32; o; o >>= 1) mx = fmaxf(mx, __shfl_xor(mx, o, 64));
    const int lane = threadIdx.x & 63, wid = threadIdx.x >> 6;
    if (lane == 0) sA[wid] = mx;
    __syncthreads();
    mx = fmaxf(fmaxf(sA[0], sA[1]), fmaxf(sA[2], sA[3])) * scale;
    float sum = 0.f;
    for (int j = threadIdx.x; j < n; j += 256) sum += __expf(srow[j] * scale - mx);
    #pragma unroll
    for (int o = 32; o; o >>= 1) sum += __shfl_xor(sum, o, 64);
    if (lane == 0) sB[wid] = sum;
    __syncthreads();
    const float inv = 1.f / (sB[0] + sB[1] + sB[2] + sB[3]);
    const int nz = ((i >> 7) + 1) << 7;
    for (int j = threadIdx.x; j < nz; j += 256) {
        float p = (j < n) ? __expf(srow[j] * scale - mx) * inv : 0.f;
        prow[j] = f2bf(p);
    }
}

// ---------------- pipelined bf16 MFMA GEMM, 128x128x32, 3-buffer counted vmcnt ----
template<int EPI, bool GATHER, int CAUSAL>
__global__ __launch_bounds__(256) void gemm2_k(
    const unsigned short* __restrict__ A_, int lda, long long zsA,
    const unsigned short* __restrict__ B_, int ldb, long long zsB,
    void* __restrict__ C_, int ldc, long long zsC,
    const float* __restrict__ bias_, long long zsBias,
    const int* __restrict__ perm_, const int* __restrict__ pcnt,
    int N, int Kp,
    unsigned short* __restrict__ q_, unsigned short* __restrict__ k_,
    unsigned short* __restrict__ vt_) {
    const int z = blockIdx.z;
    const int gm0 = blockIdx.y * 128;
    const int n0 = blockIdx.x * 128;
    if (pcnt && gm0 >= pcnt[z]) return;
    if (CAUSAL == 1 && n0 >= gm0 + 128) return;

    const unsigned short* A = A_ + (long long)z * zsA;
    const unsigned short* B = B_ + (long long)z * zsB;
    const float* bias = bias_ ? bias_ + (long long)z * zsBias : nullptr;
    const int* perm = perm_ ? perm_ + (long long)z * 1024 : nullptr;

    __shared__ unsigned short Al[3][128 * 32];
    __shared__ unsigned short Bl[3][128 * 32];

    const int tid = threadIdx.x, lane = tid & 63, wid = tid >> 6;
    const int wr = wid >> 1, wc = wid & 1;
    const int c0 = wid * 2;
    const int lrow = lane >> 2;
    const int lseg = (lane & 3) * 8;

    const unsigned short* gA[2];
    const unsigned short* gB[2];
    #pragma unroll
    for (int i = 0; i < 2; ++i) {
        const int row = (c0 + i) * 16 + lrow;
        int ar = gm0 + row;
        if (GATHER) { const int p = perm[ar]; ar = (p < 0) ? 0 : p; }
        gA[i] = A + (long long)ar * lda + lseg;
        gB[i] = B + (long long)(n0 + row) * ldb + lseg;
    }

    int nt = Kp >> 5;
    if (CAUSAL == 2) { int ke = gm0 + 128; if (ke > Kp) ke = Kp; nt = ke >> 5; }

    f32x4 acc[4][4] = {};

    // prologue: issue tiles 0 and 1 (4 vmem ops per wave per tile)
    {
        const int t1 = (nt > 1) ? 1 : 0;
        #pragma unroll
        for (int i = 0; i < 2; ++i) {
            g2l16(gA[i], &Al[0][(c0 + i) * 512]);
            g2l16(gB[i], &Bl[0][(c0 + i) * 512]);
        }
        #pragma unroll
        for (int i = 0; i < 2; ++i) {
            g2l16(gA[i] + t1 * 32, &Al[1][(c0 + i) * 512]);
            g2l16(gB[i] + t1 * 32, &Bl[1][(c0 + i) * 512]);
        }
    }

    for (int t = 0; t < nt; ++t) {
        // wait until only tile t+1's 4 loads may be outstanding -> tile t is in LDS
        asm volatile("s_waitcnt vmcnt(4)" ::: "memory");
        __builtin_amdgcn_s_barrier();
        __builtin_amdgcn_sched_barrier(0);
        // issue tile t+2 (clamped dummy at tail keeps vmcnt arithmetic uniform)
        {
            const int ts = (t + 2 < nt) ? t + 2 : nt - 1;
            const int ko = ts * 32;
            const int bi = (t + 2) % 3;
            #pragma unroll
            for (int i = 0; i < 2; ++i) {
                g2l16(gA[i] + ko, &Al[bi][(c0 + i) * 512]);
                g2l16(gB[i] + ko, &Bl[bi][(c0 + i) * 512]);
            }
        }
        const int cur = t % 3;
        const int l15 = lane & 15, kfr = (lane >> 4) * 8;
        short8 af[4], bfv[4];
        #pragma unroll
        for (int m = 0; m < 4; ++m)
            af[m] = *(const short8*)&Al[cur][(wr * 64 + m * 16 + l15) * 32 + kfr];
        #pragma unroll
        for (int n = 0; n < 4; ++n)
            bfv[n] = *(const short8*)&Bl[cur][(wc * 64 + n * 16 + l15) * 32 + kfr];
        #pragma unroll
        for (int m = 0; m < 4; ++m)
            #pragma unroll
            for (int n = 0; n < 4; ++n)
                acc[m][n] = __builtin_amdgcn_mfma_f32_16x16x32_bf16(af[m], bfv[n], acc[m][n], 0, 0, 0);
    }

    // DRAIN: wave must not reach s_endpgm with LDS-DMA in flight — pending
    // global_load_lds writes can land after this block's LDS is reassigned
    // to a newly scheduled block (the round-3 post-timing race).
    asm volatile("s_waitcnt vmcnt(0) lgkmcnt(0)" ::: "memory");

    // ---- epilogue ----
    const int l15 = lane & 15, lq = (lane >> 4) * 4;
    #pragma unroll
    for (int m = 0; m < 4; ++m) {
        const int trow = wr * 64 + m * 16 + lq;
        #pragma unroll
        for (int n = 0; n < 4; ++n) {
            const int col = n0 + wc * 64 + n * 16 + l15;
            if (col >= N) continue;
            const float bv = bias ? bias[col] : 0.f;
            if (EPI == 5) {
                const int role = col / 1352;
                const int within = col - role * 1352;
                const int hh = within / 169;
                const int dd = within - hh * 169;
                if (role == 2) {
                    us4 pk;
                    #pragma unroll
                    for (int r = 0; r < 4; ++r) pk[r] = f2bf(acc[m][n][r] + bv);
                    *(us4*)&vt_[(long long)(hh * 256 + dd) * 1024 + gm0 + trow] = pk;
                } else {
                    unsigned short* dstb = role ? k_ : q_;
                    #pragma unroll
                    for (int r = 0; r < 4; ++r)
                        dstb[(long long)(gm0 + trow + r) * QS + hh * HP + dd] =
                            f2bf(acc[m][n][r] + bv);
                }
            } else {
                #pragma unroll
                for (int r = 0; r < 4; ++r) {
                    const int grow = gm0 + trow + r;
                    const float v = acc[m][n][r] + bv;
                    if (EPI == 0) {
                        ((float*)C_)[(long long)z * zsC + (long long)grow * ldc + col] = v;
                    } else if (EPI == 1) {
                        const int tok = perm[grow];
                        ((unsigned short*)C_)[(long long)z * zsC + (long long)grow * ldc + col] =
                            (tok >= 0) ? f2bf(fmaxf(v, 0.f)) : (unsigned short)0;
                    } else if (EPI == 2) {
                        ((float*)C_)[(long long)grow * ldc + col] += v;
                    } else if (EPI == 3) {
                        const int tok = perm[grow];
                        if (tok >= 0) ((float*)C_)[(long long)tok * ldc + col] += v;
                    } else if (EPI == 6) {
                        ((unsigned short*)C_)[(long long)grow * ldc + z * 169 + col] = f2bf(v);
                    }
                }
            }
        }
    }
}

extern "C" void kernel_launch(void* const* d_in, const int* in_sizes, int n_in,
                              void* d_out, int out_size, void* d_ws, size_t ws_size,
                              hipStream_t stream) {
    const float* x     = (const float*)d_in[0];
    const float* ln1_g = (const float*)d_in[1];
    const float* ln1_b = (const float*)d_in[2];
    const float* wqkv  = (const float*)d_in[3];
    const float* bqkv  = (const float*)d_in[4];
    const float* wo    = (const float*)d_in[5];
    const float* bo    = (const float*)d_in[6];
    const float* ln2_g = (const float*)d_in[7];
    const float* ln2_b = (const float*)d_in[8];
    const float* w1    = (const float*)d_in[9];
    const float* b1    = (const float*)d_in[10];
    const float* w2    = (const float*)d_in[11];
    const float* b2    = (const float*)d_in[12];

    float* h = (float*)d_out;

    char* w = (char*)d_ws;
    auto alloc = [&](size_t bytes) { void* p = w; w += (bytes + 255) & ~255ull; return p; };
    unsigned short* lnA   = (unsigned short*)alloc((size_t)S_LEN * LDAP * 2);     // 2.82 MB
    unsigned short* qb    = (unsigned short*)alloc((size_t)S_LEN * QS * 2);       // 3.15 MB
    unsigned short* kb    = (unsigned short*)alloc((size_t)S_LEN * QS * 2);       // 3.15 MB
    unsigned short* VT    = (unsigned short*)alloc((size_t)NHEAD * 256 * 1024 * 2); // 4.19 MB
    unsigned short* obufb = (unsigned short*)alloc((size_t)S_LEN * LDAP * 2);     // 2.82 MB
    unsigned short* hid   = (unsigned short*)alloc((size_t)4096 * KP2 * 2);       // 22.3 MB
    unsigned short* wqkvT = (unsigned short*)alloc((size_t)4096 * LDAP * 2);      // 11.3 MB
    unsigned short* woT   = (unsigned short*)alloc((size_t)1408 * LDAP * 2);      // 3.87 MB
    char*           U     = (char*)alloc((size_t)61700000);                       // union
    int* perm = (int*)alloc(4096 * 4);
    int* pcnt = (int*)alloc(64);

    float*          scores = (float*)U;
    unsigned short* Pbuf   = (unsigned short*)(U + (size_t)NHEAD * 1024 * 1024 * 4);
    unsigned short* w1T    = (unsigned short*)U;
    unsigned short* w2T    = (unsigned short*)(U + (size_t)4 * 2816 * LDAP * 2);

    hipMemcpyAsync(h, x, (size_t)S_LEN * DMODEL * 4, hipMemcpyDeviceToDevice, stream);
    // q/k head-pad slots enter the scores MFMA -> must be zero
    hipMemsetAsync(qb, 0, (size_t)S_LEN * QS * 2, stream);
    hipMemsetAsync(kb, 0, (size_t)S_LEN * QS * 2, stream);
    route_k<<<1, 256, 0, stream>>>(x, perm, pcnt);

    const float scale = 1.0f / 13.0f;

    for (int l = 0; l < NLAYER; ++l) {
        const float* wqkv_l = wqkv + (long long)l * DMODEL * TD;
        const float* wo_l   = wo   + (long long)l * DMODEL * DMODEL;
        const float* w1_l   = w1   + (long long)l * 4 * DMODEL * DFFN;
        const float* w2_l   = w2   + (long long)l * 4 * DFFN * DMODEL;

        tconv_k<<<dim3(43, 127, 1), 256, 0, stream>>>(wqkv_l, wqkvT, DMODEL, TD, LDAP, 0, 0);
        tconv_k<<<dim3(43, 43, 1), 256, 0, stream>>>(wo_l, woT, DMODEL, DMODEL, LDAP, 0, 0);

        ln_k<<<1024, 256, 0, stream>>>(h, ln1_g + l * DMODEL, ln1_b + l * DMODEL, lnA, DMODEL, LDAP);
        // QKV -> split bf16 q/k (head-padded) + V transposed
        gemm2_k<5, false, 0><<<dim3(32, 8, 1), 256, 0, stream>>>(
            lnA, LDAP, 0, wqkvT, LDAP, 0, nullptr, 0, 0,
            bqkv + l * TD, 0, nullptr, nullptr, TD, LDAP, qb, kb, VT);
        // scores = q @ k^T per head (causal tiles only)
        gemm2_k<0, false, 1><<<dim3(8, 8, 8), 256, 0, stream>>>(
            qb, QS, HP, kb, QS, HP, scores, 1024, 1024 * 1024,
            nullptr, 0, nullptr, nullptr, 1024, HP, nullptr, nullptr, nullptr);
        softmax_k<<<dim3(1024, NHEAD), 256, 0, stream>>>(scores, Pbuf, scale);
        // o = P @ v per head -> compact bf16 [1024][1376]
        gemm2_k<6, false, 2><<<dim3(2, 8, 8), 256, 0, stream>>>(
            Pbuf, 1024, 1024 * 1024, VT, 1024, 256 * 1024, obufb, LDAP, 0,
            nullptr, 0, nullptr, nullptr, HDIM, 1024, nullptr, nullptr, nullptr);
        // h += o @ wo + bo
        gemm2_k<2, false, 0><<<dim3(11, 8, 1), 256, 0, stream>>>(
            obufb, LDAP, 0, woT, LDAP, 0, h, DMODEL, 0,
            bo + l * DMODEL, 0, nullptr, nullptr, DMODEL, LDAP, nullptr, nullptr, nullptr);

        tconv_k<<<dim3(43, 85, 4), 256, 0, stream>>>(
            w1_l, w1T, DMODEL, DFFN, LDAP, (long long)DMODEL * DFFN, (long long)2816 * LDAP);
        tconv_k<<<dim3(85, 43, 4), 256, 0, stream>>>(
            w2_l, w2T, DFFN, DMODEL, KP2, (long long)DFFN * DMODEL, (long long)1408 * KP2);

        ln_k<<<1024, 256, 0, stream>>>(h, ln2_g + l * DMODEL, ln2_b + l * DMODEL, lnA, DMODEL, LDAP);
        gemm2_k<1, true, 0><<<dim3(22, 8, 4), 256, 0, stream>>>(
            lnA, LDAP, 0, w1T, LDAP, (long long)2816 * LDAP,
            hid, KP2, (long long)1024 * KP2,
            b1 + (long long)l * 4 * DFFN, DFFN, perm, pcnt, DFFN, LDAP,
            nullptr, nullptr, nullptr);
        gemm2_k<3, false, 0><<<dim3(11, 8, 4), 256, 0, stream>>>(
            hid, KP2, (long long)1024 * KP2, w2T, KP2, (long long)1408 * KP2,
            h, DMODEL, 0,
            b2 + (long long)l * 4 * DMODEL, DMODEL, perm, pcnt, DMODEL, KP2,
            nullptr, nullptr, nullptr);
    }
}